// Round 1
// baseline (761.370 us; speedup 1.0000x reference)
//
#include <hip/hip_runtime.h>
#include <hip/hip_bf16.h>

#define BT    8192
#define DIM   512
#define NLAT  10000
#define LPAD  10016
#define NG    20
#define LBLK  32
#define NTILE 313   // ceil(10000/32)

typedef short bf16x8 __attribute__((ext_vector_type(8)));
typedef float f32x4  __attribute__((ext_vector_type(4)));
typedef unsigned short u16;
typedef u16 u16x8 __attribute__((ext_vector_type(8)));
typedef u16 u16x4 __attribute__((ext_vector_type(4)));

static __device__ __forceinline__ u16 f2bf(float f) {
    union { float f; unsigned u; } v; v.f = f;
    unsigned r = v.u + 0x7FFF + ((v.u >> 16) & 1);   // RNE
    return (u16)(r >> 16);
}

// ---------------- Phase 1: lang_emb = tanh(sum_valid char_table[x]) ----------------
__global__ __launch_bounds__(512) void lang_kernel(
        const int* __restrict__ x, const float* __restrict__ ct,
        float* __restrict__ lang, u16* __restrict__ qb) {
    const int tok = blockIdx.x;
    const int d   = threadIdx.x;
    const int* xr = x + tok * NG;
    float s = 0.f;
    #pragma unroll
    for (int j = 0; j < NG; ++j) {
        int c = xr[j];                 // wave-uniform -> s_load
        if (c != 1) s += ct[c * DIM + d];
    }
    float t = tanhf(s);
    lang[tok * DIM + d] = t;
    qb[tok * DIM + d]   = f2bf(t);
}

// ---------------- Phase 2: latent_mat f32 -> bf16 (zero-pad rows to LPAD) ----------
__global__ __launch_bounds__(256) void conv_kernel(
        const float* __restrict__ lm, u16* __restrict__ kv) {
    const int i = blockIdx.x * 256 + threadIdx.x;  // one per 4 elements
    const long base = (long)i * 4;
    if (base >= (long)LPAD * DIM) return;
    u16x4 o;
    if (base + 3 < (long)NLAT * DIM) {
        const float4 v = *(const float4*)(lm + base);
        o[0] = f2bf(v.x); o[1] = f2bf(v.y); o[2] = f2bf(v.z); o[3] = f2bf(v.w);
    } else {
        #pragma unroll
        for (int j = 0; j < 4; ++j) {
            long e = base + j;
            float f = (e < (long)NLAT * DIM) ? lm[e] : 0.f;
            o[j] = f2bf(f);
        }
    }
    *(u16x4*)(kv + base) = o;
}

// ---------------- Phase 3: fused flash-style softmax-attention over latents --------
__global__ __launch_bounds__(512) void attn_kernel(
        const u16* __restrict__ qb, const u16* __restrict__ kvg,
        const float* __restrict__ lang, const int* __restrict__ x,
        const float* __restrict__ ct, float* __restrict__ out) {

    __shared__ u16  kv[LBLK][DIM];        // row-major tile, col ^ ((row&7)<<3) swizzle
    __shared__ u16  kvT[DIM][LBLK + 4];   // [dim][latent], pad to 36 (72B rows, 8B aligned)
    __shared__ float Sp[2][4][16][33];    // partial scores [qs][ds][qrow][lat]
    __shared__ u16  Plds[2][64][8];       // P A-fragments per lane
    __shared__ float scale_l[2][16];      // per-row rescale factor broadcast

    const int tid  = threadIdx.x;
    const int lane = tid & 63;
    const int wv   = tid >> 6;
    const int qs   = wv >> 2;      // 0..1  (16-row q group)
    const int ds   = wv & 3;       // 0..3  (128-dim slice)
    const int g    = lane >> 4;    // lane group 0..3
    const int lr   = lane & 15;

    const int qbase = blockIdx.x * 32;

    // Q fragments (held in registers for the whole kernel): dims ds*128 .. +127
    bf16x8 qa[4];
    {
        const int qrow = qbase + qs * 16 + lr;
        const u16* qp = qb + (long)qrow * DIM + ds * 128 + g * 8;
        #pragma unroll
        for (int k = 0; k < 4; ++k)
            qa[k] = *(const bf16x8*)(qp + k * 32);
    }

    f32x4 o[8];
    #pragma unroll
    for (int i = 0; i < 8; ++i) o[i] = f32x4{0.f, 0.f, 0.f, 0.f};
    float m = -1e30f, lsum = 0.f;

    #pragma unroll 1
    for (int t = 0; t < NTILE; ++t) {
        const int lb = t * LBLK;

        // ---- Phase A: stage tile (global bf16 -> LDS, swizzled) ----
        #pragma unroll
        for (int i = 0; i < 4; ++i) {
            int flat = tid + i * 512;        // 16B chunk id, 0..2047
            int r    = flat >> 6;            // latent row 0..31
            int c8   = flat & 63;            // chunk in row
            u16x8 v = *(const u16x8*)(kvg + (long)(lb + r) * DIM + c8 * 8);
            int cs = (c8 * 8) ^ ((r & 7) << 3);
            *(u16x8*)(&kv[r][cs]) = v;
        }
        __syncthreads();

        // ---- Phase B: build transposed copy kvT[dim][latent] ----
        {
            const int d0 = tid;              // 512 threads = 512 dims
            #pragma unroll
            for (int lg = 0; lg < 4; ++lg) {
                u16 v[8];
                #pragma unroll
                for (int j = 0; j < 8; ++j)
                    v[j] = kv[lg * 8 + j][d0 ^ (j << 3)];
                u16x4 lo = { v[0], v[1], v[2], v[3] };
                u16x4 hi = { v[4], v[5], v[6], v[7] };
                *(u16x4*)(&kvT[d0][lg * 8])     = lo;
                *(u16x4*)(&kvT[d0][lg * 8 + 4]) = hi;
            }
        }

        // ---- QK^T partials over this wave's 128-dim slice ----
        f32x4 sacc[2];
        sacc[0] = f32x4{0.f,0.f,0.f,0.f};
        sacc[1] = f32x4{0.f,0.f,0.f,0.f};
        #pragma unroll
        for (int cf = 0; cf < 2; ++cf) {
            const int row = cf * 16 + lr;
            const int sw  = (row & 7) << 3;
            #pragma unroll
            for (int k = 0; k < 4; ++k) {
                bf16x8 bf = *(const bf16x8*)(&kv[row][(ds * 128 + k * 32 + g * 8) ^ sw]);
                sacc[cf] = __builtin_amdgcn_mfma_f32_16x16x32_bf16(qa[k], bf, sacc[cf], 0, 0, 0);
            }
        }
        #pragma unroll
        for (int cf = 0; cf < 2; ++cf)
            #pragma unroll
            for (int r = 0; r < 4; ++r)
                Sp[qs][ds][g * 4 + r][cf * 16 + lr] = sacc[cf][r];
        __syncthreads();

        // ---- softmax (one wave per q-group) ----
        if (ds == 0) {
            float sv[8];
            #pragma unroll
            for (int j = 0; j < 8; ++j) {
                int c = g * 8 + j;
                float s = Sp[qs][0][lr][c] + Sp[qs][1][lr][c]
                        + Sp[qs][2][lr][c] + Sp[qs][3][lr][c];
                if (lb + c >= NLAT) s = -1e30f;
                sv[j] = s;
            }
            float tm = sv[0];
            #pragma unroll
            for (int j = 1; j < 8; ++j) tm = fmaxf(tm, sv[j]);
            tm = fmaxf(tm, __shfl_xor(tm, 16));
            tm = fmaxf(tm, __shfl_xor(tm, 32));
            const float mn = fmaxf(m, tm);
            const float scale = __expf(m - mn);
            float ps = 0.f;
            u16x8 pu;
            #pragma unroll
            for (int j = 0; j < 8; ++j) {
                float p = __expf(sv[j] - mn);
                ps += p;
                pu[j] = f2bf(p);
            }
            ps += __shfl_xor(ps, 16);
            ps += __shfl_xor(ps, 32);
            lsum = lsum * scale + ps;
            m = mn;
            *(u16x8*)(&Plds[qs][lane][0]) = pu;
            if (lane < 16) scale_l[qs][lane] = scale;
        }
        __syncthreads();

        // ---- rescale O + PV accumulate ----
        float scr[4];
        #pragma unroll
        for (int r = 0; r < 4; ++r) scr[r] = scale_l[qs][g * 4 + r];
        #pragma unroll
        for (int cf = 0; cf < 8; ++cf)
            #pragma unroll
            for (int r = 0; r < 4; ++r) o[cf][r] *= scr[r];

        bf16x8 pa;
        {
            u16x8 pv8 = *(const u16x8*)(&Plds[qs][lane][0]);
            #pragma unroll
            for (int j = 0; j < 8; ++j) pa[j] = (short)pv8[j];
        }
        #pragma unroll
        for (int cf = 0; cf < 8; ++cf) {
            const int dim = ds * 128 + cf * 16 + lr;
            u16x4 blo = *(const u16x4*)(&kvT[dim][g * 8]);
            u16x4 bhi = *(const u16x4*)(&kvT[dim][g * 8 + 4]);
            bf16x8 bf = { (short)blo[0], (short)blo[1], (short)blo[2], (short)blo[3],
                          (short)bhi[0], (short)bhi[1], (short)bhi[2], (short)bhi[3] };
            o[cf] = __builtin_amdgcn_mfma_f32_16x16x32_bf16(pa, bf, o[cf], 0, 0, 0);
        }
        __syncthreads();
    }

    // ---- epilogue: out = lang + O/l, then first-token override ----
    __syncthreads();
    if (ds == 0 && lane < 16) scale_l[qs][lane] = 1.f / lsum;
    __syncthreads();
    float li[4];
    #pragma unroll
    for (int r = 0; r < 4; ++r) li[r] = scale_l[qs][g * 4 + r];

    #pragma unroll
    for (int cf = 0; cf < 8; ++cf) {
        const int col = ds * 128 + cf * 16 + lr;
        #pragma unroll
        for (int r = 0; r < 4; ++r) {
            const int qrow = qbase + qs * 16 + g * 4 + r;
            float val = lang[(long)qrow * DIM + col] + o[cf][r] * li[r];
            const int first = x[qrow * NG];
            if (first < 4) val = ct[first * DIM + col];
            out[(long)qrow * DIM + col] = val;
        }
    }
}

extern "C" void kernel_launch(void* const* d_in, const int* in_sizes, int n_in,
                              void* d_out, int out_size, void* d_ws, size_t ws_size,
                              hipStream_t stream) {
    const int*   x  = (const int*)d_in[0];
    const float* ct = (const float*)d_in[1];
    const float* lm = (const float*)d_in[2];
    float* out = (float*)d_out;

    char* ws = (char*)d_ws;
    u16*   qbf  = (u16*)ws;                                   // 8 MB
    float* lang = (float*)(ws + (size_t)BT * DIM * 2);        // 16 MB
    u16*   kvg  = (u16*)(ws + (size_t)BT * DIM * 2 + (size_t)BT * DIM * 4); // 10 MB

    lang_kernel<<<BT, 512, 0, stream>>>(x, ct, lang, qbf);
    conv_kernel<<<(LPAD * DIM / 4 + 255) / 256, 256, 0, stream>>>(lm, kvg);
    attn_kernel<<<BT / 32, 512, 0, stream>>>(qbf, kvg, lang, x, ct, out);
}

// Round 2
// 493.802 us; speedup vs baseline: 1.5419x; 1.5419x over previous
//
#include <hip/hip_runtime.h>

#define BT   8192
#define DIM  512
#define NLAT 10000
#define LPAD 10112   // 79 * 128
#define NG   20

typedef short bf16x8 __attribute__((ext_vector_type(8)));
typedef float f32x4  __attribute__((ext_vector_type(4)));
typedef unsigned short u16;
typedef u16 u16x8 __attribute__((ext_vector_type(8)));

static __device__ __forceinline__ u16 f2bf(float f) {
    union { float f; unsigned u; } v; v.f = f;
    unsigned r = v.u + 0x7FFF + ((v.u >> 16) & 1);   // RNE
    return (u16)(r >> 16);
}

static __device__ __forceinline__ void gload16(const void* g, void* l) {
    __builtin_amdgcn_global_load_lds(
        (const __attribute__((address_space(1))) unsigned int*)g,
        (__attribute__((address_space(3))) unsigned int*)l,
        16, 0, 0);
}

// ---------------- lang_emb = tanh(sum_valid char_table[x]); also bf16 copy ----------
__global__ __launch_bounds__(512) void lang_kernel(
        const int* __restrict__ x, const float* __restrict__ ct,
        float* __restrict__ lang, u16* __restrict__ qb) {
    const int tok = blockIdx.x;
    const int d   = threadIdx.x;
    const int* xr = x + tok * NG;
    float s = 0.f;
    #pragma unroll
    for (int j = 0; j < NG; ++j) {
        int c = xr[j];                 // wave-uniform -> s_load
        if (c != 1) s += ct[c * DIM + d];
    }
    float t = tanhf(s);
    lang[(long)tok * DIM + d] = t;
    qb[(long)tok * DIM + d]   = f2bf(t);
}

// -------- latent_mat f32 -> kvg bf16 [LPAD][DIM] and latT bf16 [DIM][LPAD] ----------
__global__ __launch_bounds__(256) void conv_kernel(
        const float* __restrict__ lm, u16* __restrict__ kvg, u16* __restrict__ latT) {
    __shared__ u16 tile[64][514];
    const int lb = blockIdx.x * 64;
    const int t  = threadIdx.x;

    #pragma unroll 4
    for (int i = 0; i < 16; ++i) {
        int ch  = t + i * 256;
        int r   = ch >> 6;
        int c8  = ch & 63;
        int row = lb + r;
        u16x8 v = {0,0,0,0,0,0,0,0};
        if (row < NLAT) {
            const float* src = lm + (long)row * DIM + c8 * 8;
            float4 a = *(const float4*)src;
            float4 b = *(const float4*)(src + 4);
            v[0]=f2bf(a.x); v[1]=f2bf(a.y); v[2]=f2bf(a.z); v[3]=f2bf(a.w);
            v[4]=f2bf(b.x); v[5]=f2bf(b.y); v[6]=f2bf(b.z); v[7]=f2bf(b.w);
        }
        *(u16x8*)(kvg + (long)row * DIM + c8 * 8) = v;
        #pragma unroll
        for (int j = 0; j < 8; ++j) tile[r][c8 * 8 + j] = v[j];
    }
    __syncthreads();
    #pragma unroll 4
    for (int i = 0; i < 16; ++i) {
        int ch = t + i * 256;
        int d  = ch >> 3;
        int c8 = ch & 7;
        u16x8 v;
        #pragma unroll
        for (int j = 0; j < 8; ++j) v[j] = tile[c8 * 8 + j][d];
        *(u16x8*)(latT + (long)d * LPAD + lb + c8 * 8) = v;
    }
}

// -------- GEMM1: P = exp(Q @ latT) masked, bf16; rowsum += row partials ------------
// C[m][n] = sum_k Q[m][k] * kvg[n][k]   (NT), M=8192, N=np*128, K=512
__global__ __launch_bounds__(256) void gemm1_kernel(
        const u16* __restrict__ Q, const u16* __restrict__ L,
        u16* __restrict__ P, float* __restrict__ rowsum,
        int n0_global, int npanels, int pstride) {
    __shared__ u16 As[128 * 64];
    __shared__ u16 Bs[128 * 64];

    const int nwg = 64 * npanels;          // % 8 == 0 always
    const int cpx = nwg >> 3;
    const int bid = blockIdx.x;
    const int wg  = (bid & 7) * cpx + (bid >> 3);
    const int mb  = wg / npanels, nb = wg % npanels;
    const long m0    = (long)mb * 128;
    const int  ncol0 = n0_global + nb * 128;

    const u16* Ag = Q + m0 * DIM;
    const u16* Bg = L + (long)ncol0 * DIM;

    const int t = threadIdx.x, lane = t & 63, w = t >> 6;
    const int wm = w >> 1, wn = w & 1;
    const int g = lane >> 4, lr = lane & 15;
    const int srow = lane >> 3, scol = (lane & 7) * 8;

    f32x4 acc[4][4];
    #pragma unroll
    for (int m = 0; m < 4; ++m)
        #pragma unroll
        for (int n = 0; n < 4; ++n) acc[m][n] = f32x4{0.f,0.f,0.f,0.f};

    #pragma unroll 1
    for (int kt = 0; kt < DIM / 64; ++kt) {
        const int k0 = kt * 64;
        #pragma unroll
        for (int i = 0; i < 4; ++i) {
            int c = i * 4 + w;
            gload16(Ag + (long)(c * 8 + srow) * DIM + k0 + scol, &As[c * 512]);
            gload16(Bg + (long)(c * 8 + srow) * DIM + k0 + scol, &Bs[c * 512]);
        }
        __syncthreads();
        #pragma unroll
        for (int kc = 0; kc < 2; ++kc) {
            bf16x8 af[4], bfr[4];
            #pragma unroll
            for (int m = 0; m < 4; ++m)
                af[m] = *(const bf16x8*)&As[(wm * 64 + m * 16 + lr) * 64 + kc * 32 + g * 8];
            #pragma unroll
            for (int n = 0; n < 4; ++n)
                bfr[n] = *(const bf16x8*)&Bs[(wn * 64 + n * 16 + lr) * 64 + kc * 32 + g * 8];
            #pragma unroll
            for (int m = 0; m < 4; ++m)
                #pragma unroll
                for (int n = 0; n < 4; ++n)
                    acc[m][n] = __builtin_amdgcn_mfma_f32_16x16x32_bf16(af[m], bfr[n], acc[m][n], 0, 0, 0);
        }
        __syncthreads();
    }

    // epilogue: exp, mask, bf16 store, row-sum atomics
    #pragma unroll
    for (int m = 0; m < 4; ++m) {
        float sv[4] = {0.f, 0.f, 0.f, 0.f};
        const long rowb = m0 + wm * 64 + m * 16 + g * 4;
        #pragma unroll
        for (int n = 0; n < 4; ++n) {
            const int col  = ncol0 + wn * 64 + n * 16 + lr;
            const bool ok  = (col < NLAT);
            const int pcol = col - n0_global;
            #pragma unroll
            for (int r = 0; r < 4; ++r) {
                float p = ok ? __expf(acc[m][n][r]) : 0.f;
                P[(rowb + r) * (long)pstride + pcol] = f2bf(p);
                sv[r] += p;
            }
        }
        #pragma unroll
        for (int r = 0; r < 4; ++r) {
            float s = sv[r];
            s += __shfl_xor(s, 1); s += __shfl_xor(s, 2);
            s += __shfl_xor(s, 4); s += __shfl_xor(s, 8);
            if (lr == 0) atomicAdd(&rowsum[rowb + r], s);
        }
    }
}

// -------- GEMM2: out(+)= P @ latTᵀ  (NT), M=8192, N=512, K=kcols --------------------
__global__ __launch_bounds__(256) void gemm2_kernel(
        const u16* __restrict__ P, const u16* __restrict__ LT,
        float* __restrict__ out, int pstride, int kcols, int kofs, int accum) {
    __shared__ u16 As[128 * 64];
    __shared__ u16 Bs[128 * 64];

    const int bid = blockIdx.x;                 // 256 blocks
    const int wg  = (bid & 7) * 32 + (bid >> 3);
    const int mb  = wg >> 2, nb = wg & 3;
    const long m0    = (long)mb * 128;
    const int  ncol0 = nb * 128;

    const u16* Ag = P  + m0 * (long)pstride;
    const u16* Bg = LT + (long)ncol0 * LPAD + kofs;

    const int t = threadIdx.x, lane = t & 63, w = t >> 6;
    const int wm = w >> 1, wn = w & 1;
    const int g = lane >> 4, lr = lane & 15;
    const int srow = lane >> 3, scol = (lane & 7) * 8;

    f32x4 acc[4][4];
    #pragma unroll
    for (int m = 0; m < 4; ++m)
        #pragma unroll
        for (int n = 0; n < 4; ++n) acc[m][n] = f32x4{0.f,0.f,0.f,0.f};

    #pragma unroll 1
    for (int kt = 0; kt < kcols / 64; ++kt) {
        const int k0 = kt * 64;
        #pragma unroll
        for (int i = 0; i < 4; ++i) {
            int c = i * 4 + w;
            gload16(Ag + (long)(c * 8 + srow) * pstride + k0 + scol, &As[c * 512]);
            gload16(Bg + (long)(c * 8 + srow) * LPAD    + k0 + scol, &Bs[c * 512]);
        }
        __syncthreads();
        #pragma unroll
        for (int kc = 0; kc < 2; ++kc) {
            bf16x8 af[4], bfr[4];
            #pragma unroll
            for (int m = 0; m < 4; ++m)
                af[m] = *(const bf16x8*)&As[(wm * 64 + m * 16 + lr) * 64 + kc * 32 + g * 8];
            #pragma unroll
            for (int n = 0; n < 4; ++n)
                bfr[n] = *(const bf16x8*)&Bs[(wn * 64 + n * 16 + lr) * 64 + kc * 32 + g * 8];
            #pragma unroll
            for (int m = 0; m < 4; ++m)
                #pragma unroll
                for (int n = 0; n < 4; ++n)
                    acc[m][n] = __builtin_amdgcn_mfma_f32_16x16x32_bf16(af[m], bfr[n], acc[m][n], 0, 0, 0);
        }
        __syncthreads();
    }

    #pragma unroll
    for (int m = 0; m < 4; ++m)
        #pragma unroll
        for (int n = 0; n < 4; ++n) {
            const int col = ncol0 + wn * 64 + n * 16 + lr;
            #pragma unroll
            for (int r = 0; r < 4; ++r) {
                const long row = m0 + wm * 64 + m * 16 + g * 4 + r;
                float v = acc[m][n][r];
                if (accum) v += out[row * DIM + col];
                out[row * DIM + col] = v;
            }
        }
}

// -------- final: out = out/rowsum + lang; first-token override ----------------------
__global__ __launch_bounds__(256) void final_kernel(
        float* __restrict__ out, const float* __restrict__ lang,
        const float* __restrict__ rowsum, const int* __restrict__ x,
        const float* __restrict__ ct) {
    const int tok  = blockIdx.x;
    const float inv = 1.f / rowsum[tok];
    const int first = x[tok * NG];
    #pragma unroll
    for (int i = 0; i < 2; ++i) {
        const int col = threadIdx.x + i * 256;
        float v = out[(long)tok * DIM + col] * inv + lang[(long)tok * DIM + col];
        if (first < 4) v = ct[first * DIM + col];
        out[(long)tok * DIM + col] = v;
    }
}

extern "C" void kernel_launch(void* const* d_in, const int* in_sizes, int n_in,
                              void* d_out, int out_size, void* d_ws, size_t ws_size,
                              hipStream_t stream) {
    const int*   x  = (const int*)d_in[0];
    const float* ct = (const float*)d_in[1];
    const float* lm = (const float*)d_in[2];
    float* out = (float*)d_out;

    char* ws = (char*)d_ws;
    size_t off = 0;
    u16*   qb   = (u16*)(ws + off);   off += (size_t)BT * DIM * 2;     // 8 MB
    float* lang = (float*)(ws + off); off += (size_t)BT * DIM * 4;     // 16 MB
    u16*   kvg  = (u16*)(ws + off);   off += (size_t)LPAD * DIM * 2;   // 10.35 MB
    u16*   latT = (u16*)(ws + off);   off += (size_t)DIM * LPAD * 2;   // 10.35 MB
    float* rowsum = (float*)(ws + off); off += (size_t)BT * 4;         // 32 KB
    u16*   P    = (u16*)(ws + off);
    const size_t fixed = off;

    // choose latent chunking to fit ws
    const int panels_total = LPAD / 128;                   // 79
    const size_t per_panel = (size_t)BT * 128 * 2;         // 2 MB
    int panels_per_chunk = panels_total;
    if (ws_size > fixed) {
        size_t avail = ws_size - fixed;
        size_t p = avail / per_panel;
        if (p < (size_t)panels_total) panels_per_chunk = (int)(p < 1 ? 1 : p);
    } else {
        panels_per_chunk = 1;
    }
    const int pstride = panels_per_chunk * 128;

    hipMemsetAsync(rowsum, 0, (size_t)BT * 4, stream);
    lang_kernel<<<BT, 512, 0, stream>>>(x, ct, lang, qb);
    conv_kernel<<<LPAD / 64, 256, 0, stream>>>(lm, kvg, latT);

    for (int cs = 0; cs < panels_total; cs += panels_per_chunk) {
        const int np = (panels_total - cs < panels_per_chunk) ? (panels_total - cs)
                                                              : panels_per_chunk;
        gemm1_kernel<<<64 * np, 256, 0, stream>>>(qb, kvg, P, rowsum,
                                                  cs * 128, np, pstride);
        gemm2_kernel<<<256, 256, 0, stream>>>(P, latT, out, pstride,
                                              np * 128, cs * 128, cs > 0 ? 1 : 0);
    }
    final_kernel<<<BT, 256, 0, stream>>>(out, lang, rowsum, x, ct);
}